// Round 4
// baseline (731.054 us; speedup 1.0000x reference)
//
#include <hip/hip_runtime.h>

#define B_ 128
#define T_ 2048
#define K_ 64
#define NF_ 256
#define L2E 1.44269504088896340736f
#define LN2 0.69314718055994530942f

__device__ __forceinline__ float rfl_f(float x) {
    return __int_as_float(__builtin_amdgcn_readfirstlane(__float_as_int(x)));
}
__device__ __forceinline__ float rdl_f(float x, int i) {
    return __int_as_float(__builtin_amdgcn_readlane(__float_as_int(x), i));
}

// Blocks [0, B_): one wave per batch element, CRF forward scan + gold score.
// Blocks [B_, B_+NF_): focal-scale partial sums (data-parallel).
__global__ __launch_bounds__(64) void fcrf_main(
    const float* __restrict__ em, const int* __restrict__ lab,
    const int* __restrict__ msk, const float* __restrict__ trans,
    const float* __restrict__ stv, const float* __restrict__ env,
    float* __restrict__ ws)
{
    __shared__ float trans_sh[K_ * K_];
    const int lane = threadIdx.x;
    const int blk = blockIdx.x;

    if (blk < B_) {
        // ---------------- CRF scan path ----------------
        const int b = blk;
        const float* emb = em + (size_t)b * T_ * K_;
        const int* labb = lab + (size_t)b * T_;
        const int* mb = msk + (size_t)b * T_;

        // Lane j holds column j of W = exp(trans): w[i] = exp(trans[i][j]).
        float w[K_];
        #pragma unroll
        for (int i = 0; i < K_; ++i) {
            float tv = trans[i * K_ + lane];
            trans_sh[i * K_ + lane] = tv;   // raw trans for gold-path score
            w[i] = __builtin_amdgcn_exp2f(tv * L2E);
        }
        float endv = env[lane];
        float alpha = stv[lane] + emb[lane];   // alpha0 (unmasked, per reference)
        __syncthreads();  // one-time; trans_sh ready before loop

        float snorm = rfl_f(alpha);            // cheap approximate normalizer
        int tag0 = labb[0];
        tag0 = (tag0 == -100) ? 0 : tag0;
        float sc = (lane == tag0) ? alpha : 0.f;  // start[tag0] + em[0,tag0]
        int ptag = tag0;

        // Prefetch pipeline: groups of 4 steps, loads issued one group ahead.
        float emc[4], emn[4];
        int tgc[4], tgn[4], mc[4], mn[4];
        #pragma unroll
        for (int j = 0; j < 4; ++j) {
            int t = 1 + j;
            emc[j] = emb[t * K_ + lane];
            int lb = labb[t];
            mc[j] = (lb != -100) & (mb[t] != 0);
            tgc[j] = (lb == -100) ? 0 : lb;
        }

        // Steps t = 1 .. 2048 (t=2048 is mask-forced to no-op); 512 groups of 4.
        for (int g = 0; g < 512; ++g) {
            #pragma unroll
            for (int j = 0; j < 4; ++j) {
                int t = 1 + 4 * (g + 1) + j;
                int valid = (t < T_) ? 1 : 0;
                int tl = valid ? t : (T_ - 1);       // clamp: stay in-bounds
                emn[j] = emb[tl * K_ + lane];
                int lb = labb[tl];
                mn[j] = valid & (lb != -100) & (mb[tl] != 0);
                tgn[j] = (lb == -100) ? 0 : lb;
            }
            #pragma unroll
            for (int j = 0; j < 4; ++j) {
                // e_j = exp(alpha_j - snorm); bounded by e^~11, fp32-safe.
                float e = __builtin_amdgcn_exp2f((alpha - snorm) * L2E);
                // mat-vec: sum_i e_i * W[i][lane], e_i via readlane broadcast.
                float a0 = 0.f, a1 = 0.f, a2 = 0.f, a3 = 0.f;
                #pragma unroll
                for (int i = 0; i < K_; i += 4) {
                    a0 = fmaf(rdl_f(e, i + 0), w[i + 0], a0);
                    a1 = fmaf(rdl_f(e, i + 1), w[i + 1], a1);
                    a2 = fmaf(rdl_f(e, i + 2), w[i + 2], a2);
                    a3 = fmaf(rdl_f(e, i + 3), w[i + 3], a3);
                }
                float s = (a0 + a1) + (a2 + a3);
                float emv = emc[j];
                float nxt = fmaf(__builtin_amdgcn_logf(s), LN2, snorm) + emv;
                bool m = (mc[j] != 0);
                alpha = m ? nxt : alpha;
                // gold-path score (off critical path)
                int tg = tgc[j];
                float tv = trans_sh[ptag * K_ + lane];
                float add = (lane == tg) ? (emv + tv) : 0.f;
                sc += m ? add : 0.f;
                ptag = m ? tg : ptag;
                snorm = rfl_f(alpha);
            }
            #pragma unroll
            for (int j = 0; j < 4; ++j) { emc[j] = emn[j]; tgc[j] = tgn[j]; mc[j] = mn[j]; }
        }

        // end contributions
        sc += (lane == ptag) ? endv : 0.f;
        #pragma unroll
        for (int off = 1; off < 64; off <<= 1) sc += __shfl_xor(sc, off, 64);

        // logZ = logsumexp(alpha + end) with exact max (done once)
        float x = alpha + endv;
        float mx = x;
        #pragma unroll
        for (int off = 1; off < 64; off <<= 1) mx = fmaxf(mx, __shfl_xor(mx, off, 64));
        float se = __builtin_amdgcn_exp2f((x - mx) * L2E);
        #pragma unroll
        for (int off = 1; off < 64; off <<= 1) se += __shfl_xor(se, off, 64);
        float logZ = fmaf(__builtin_amdgcn_logf(se), LN2, mx);

        if (lane == 0) ws[b] = sc - logZ;   // llh_b
    } else {
        // ---------------- focal-scale path ----------------
        const int fb = blk - B_;
        const float4* em4 = (const float4*)em;
        const int sub = lane >> 4;       // which of 4 rows
        const int cg = lane & 15;        // 16 lanes cover one row (4 cols each)
        float facc = 0.f, cacc = 0.f;
        const int base = fb * (B_ * T_ / NF_);   // 1024 rows per block
        for (int it = 0; it < (B_ * T_ / NF_) / 4; ++it) {
            int row = base + it * 4 + sub;
            float4 v = em4[row * (K_ / 4) + cg];
            int lb = lab[row];
            int vm = (lb != -100) & (msk[row] != 0);
            int tg = (lb == -100) ? 0 : lb;
            float mx = fmaxf(fmaxf(v.x, v.y), fmaxf(v.z, v.w));
            #pragma unroll
            for (int off = 1; off < 16; off <<= 1) mx = fmaxf(mx, __shfl_xor(mx, off, 64));
            float se = __builtin_amdgcn_exp2f((v.x - mx) * L2E)
                     + __builtin_amdgcn_exp2f((v.y - mx) * L2E)
                     + __builtin_amdgcn_exp2f((v.z - mx) * L2E)
                     + __builtin_amdgcn_exp2f((v.w - mx) * L2E);
            int c0 = cg * 4;
            float sel = ((c0 + 0 == tg) ? v.x : 0.f) + ((c0 + 1 == tg) ? v.y : 0.f)
                      + ((c0 + 2 == tg) ? v.z : 0.f) + ((c0 + 3 == tg) ? v.w : 0.f);
            #pragma unroll
            for (int off = 1; off < 16; off <<= 1) {
                se += __shfl_xor(se, off, 64);
                sel += __shfl_xor(sel, off, 64);
            }
            float p = __builtin_amdgcn_exp2f((sel - mx) * L2E) / se;
            float fw = (1.f - p) * (1.f - p);
            if (cg == 0) {
                facc += vm ? fw : 0.f;
                cacc += vm ? 1.f : 0.f;
            }
        }
        #pragma unroll
        for (int off = 1; off < 64; off <<= 1) {
            facc += __shfl_xor(facc, off, 64);
            cacc += __shfl_xor(cacc, off, 64);
        }
        if (lane == 0) {
            ws[B_ + 2 * fb] = facc;
            ws[B_ + 2 * fb + 1] = cacc;
        }
    }
}

__global__ __launch_bounds__(64) void fcrf_final(const float* __restrict__ ws,
                                                 float* __restrict__ out)
{
    const int lane = threadIdx.x;
    float llh = ws[lane] + ws[64 + lane];
    float f = 0.f, c = 0.f;
    #pragma unroll
    for (int k = 0; k < NF_ / 64; ++k) {
        int i = lane + 64 * k;
        f += ws[B_ + 2 * i];
        c += ws[B_ + 2 * i + 1];
    }
    #pragma unroll
    for (int off = 1; off < 64; off <<= 1) {
        llh += __shfl_xor(llh, off, 64);
        f += __shfl_xor(f, off, 64);
        c += __shfl_xor(c, off, 64);
    }
    if (lane == 0) {
        float crf = -(llh * (1.0f / B_));
        float scale = f / fmaxf(c, 1.f);
        scale = fmaxf(scale, 0.1f);
        out[0] = crf * scale;
    }
}

extern "C" void kernel_launch(void* const* d_in, const int* in_sizes, int n_in,
                              void* d_out, int out_size, void* d_ws, size_t ws_size,
                              hipStream_t stream) {
    const float* em = (const float*)d_in[0];
    const int* lab = (const int*)d_in[1];
    const int* msk = (const int*)d_in[2];  // harness stores jnp bool as int32
    const float* trans = (const float*)d_in[3];
    const float* stv = (const float*)d_in[4];
    const float* env = (const float*)d_in[5];
    float* ws = (float*)d_ws;
    float* out = (float*)d_out;

    fcrf_main<<<dim3(B_ + NF_), dim3(64), 0, stream>>>(em, lab, msk, trans, stv, env, ws);
    fcrf_final<<<dim3(1), dim3(64), 0, stream>>>(ws, out);
}